// Round 5
// baseline (428.670 us; speedup 1.0000x reference)
//
#include <hip/hip_runtime.h>
#include <hip/hip_bf16.h>

typedef __attribute__((ext_vector_type(4))) float f32x4;
typedef __attribute__((ext_vector_type(8))) short bf16x8;
typedef __attribute__((ext_vector_type(4))) unsigned u32x4;

__device__ __forceinline__ short f2b(float f) {  // fp32 -> bf16 bits, RNE
  unsigned u = __builtin_bit_cast(unsigned, f);
  u += 0x7FFFu + ((u >> 16) & 1u);
  return (short)(u >> 16);
}
__device__ __forceinline__ float b2f(short s) {
  unsigned u = ((unsigned)(unsigned short)s) << 16;
  return __builtin_bit_cast(float, u);
}
__device__ __forceinline__ unsigned cvtpk(float lo, float hi) {  // 2xf32->2xbf16
  unsigned r;
  asm("v_cvt_pk_bf16_f32 %0, %1, %2" : "=v"(r) : "v"(lo), "v"(hi));
  return r;
}

__device__ __forceinline__ void async16(const void* g, void* l) {
  __builtin_amdgcn_global_load_lds(
      (const __attribute__((address_space(1))) void*)g,
      (__attribute__((address_space(3))) void*)l, 16, 0, 0);
}

#define BM 128
#define BN 128
#define BK 64

// Convert fp32 inputs to bf16 workspace: X (8388608 el) then Wq/Wk/Wv/Wo
// (4194304 el each), laid out consecutively from `dst`.
__global__ __launch_bounds__(256) void cvt_kernel(
    const float* __restrict__ X, const float* __restrict__ Wq,
    const float* __restrict__ Wk, const float* __restrict__ Wv,
    const float* __restrict__ Wo, short* __restrict__ dst) {
  const size_t u = (size_t)blockIdx.x * 256 + threadIdx.x;  // unit of 8 elems
  const float* src;
  short* d;
  size_t off;
  if (u < 1048576) {                // X: 1048576 units
    src = X; d = dst; off = u * 8;
  } else {
    const size_t j = u - 1048576;   // 4 x 524288 units
    const int ten = (int)(j >> 19);
    off = (j & 524287) * 8;
    src = (ten == 0) ? Wq : (ten == 1) ? Wk : (ten == 2) ? Wv : Wo;
    d = dst + 8388608 + (size_t)ten * 4194304;
  }
  const f32x4 lo = *(const f32x4*)(src + off);
  const f32x4 hi = *(const f32x4*)(src + off + 4);
  bf16x8 v;
#pragma unroll
  for (int i = 0; i < 4; ++i) { v[i] = f2b(lo[i]); v[i + 4] = f2b(hi[i]); }
  *(bf16x8*)(d + off) = v;
}

// C = A[M,K] @ B[N,K]^T, all-bf16 operands, global_load_lds staging (m97).
// MODE 0: z selects Wq/Wk/Wv; epilogue scatters Q,K [B,H,S,D], V^T [B,H,D,S].
// MODE 1: fp32 row-major output [M,2048] -> d_out.
template <int MODE>
__global__ __launch_bounds__(256, 2) void gemm_kernel(
    const short* __restrict__ A,
    const short* __restrict__ B0,
    const short* __restrict__ B1,
    const short* __restrict__ B2,
    void* __restrict__ O0,
    short* __restrict__ O1,
    short* __restrict__ O2) {
  constexpr int K = 2048;
  const int m0 = blockIdx.x * BM;
  const int n0 = blockIdx.y * BN;
  const short* B;
  if (MODE == 0) {
    const int wsel = blockIdx.z;
    B = (wsel == 0) ? B0 : ((wsel == 1) ? B1 : B2);
  } else {
    B = B0;
  }

  __shared__ __align__(16) short As[BM * BK];  // [row][8 granules, XOR-swizzled]
  __shared__ __align__(16) short Bs[BN * BK];

  const int t = threadIdx.x;
  const int wave = t >> 6;
  const int lane = t & 63;
  const int qd = lane >> 4;  // quad 0..3
  const int ln = lane & 15;
  const int wr = wave >> 1;
  const int wc = wave & 1;

  const f32x4 zero = {0.f, 0.f, 0.f, 0.f};
  f32x4 acc[4][4];
#pragma unroll
  for (int i = 0; i < 4; ++i)
#pragma unroll
    for (int j = 0; j < 4; ++j) acc[i][j] = zero;

  // staging: round r covers row r*32 + (t>>3); LDS slot t&7 holds global
  // granule (t&7)^(row&7). LDS elem for (t, r): r*2048 + t*8 = row*64 + slot*8.
  // LDS dest = wave-uniform base + lane*16B (async16 constraint) ✓
  const int srow = t >> 3;
  const int sgp = (t & 7) ^ (srow & 7);
  const short* Ag = A + (size_t)(m0 + srow) * K + sgp * 8;
  const short* Bg = B + (size_t)(n0 + srow) * K + sgp * 8;
  short* Asw = &As[wave * 512];
  short* Bsw = &Bs[wave * 512];

  for (int k0 = 0; k0 < K; k0 += BK) {
    __syncthreads();
#pragma unroll
    for (int r = 0; r < 4; ++r) {
      async16(Ag + (size_t)(r * 32) * K + k0, Asw + r * 2048);
      async16(Bg + (size_t)(r * 32) * K + k0, Bsw + r * 2048);
    }
    __syncthreads();

    bf16x8 af[2][4], bf[2][4];
#pragma unroll
    for (int kc = 0; kc < 2; ++kc) {
#pragma unroll
      for (int i = 0; i < 4; ++i) {
        const int m = wr * 64 + i * 16 + ln;
        af[kc][i] = *(const bf16x8*)&As[m * BK + (((kc * 4 + qd) ^ (m & 7)) << 3)];
        const int n = wc * 64 + i * 16 + ln;
        bf[kc][i] = *(const bf16x8*)&Bs[n * BK + (((kc * 4 + qd) ^ (n & 7)) << 3)];
      }
    }
#pragma unroll
    for (int kc = 0; kc < 2; ++kc)
#pragma unroll
      for (int i = 0; i < 4; ++i)
#pragma unroll
        for (int j = 0; j < 4; ++j)
          acc[i][j] = __builtin_amdgcn_mfma_f32_16x16x32_bf16(af[kc][i], bf[kc][j],
                                                              acc[i][j], 0, 0, 0);
  }

  // epilogue; C/D layout: col = lane&15, row = quad*4 + reg (m89/m91 verified)
#pragma unroll
  for (int i = 0; i < 4; ++i) {
#pragma unroll
    for (int j = 0; j < 4; ++j) {
      const int n = n0 + wc * 64 + j * 16 + ln;
#pragma unroll
      for (int rr = 0; rr < 4; ++rr) {
        const int m = m0 + wr * 64 + i * 16 + qd * 4 + rr;
        if (MODE == 1) {
          ((float*)O0)[(size_t)m * 2048 + n] = acc[i][j][rr];  // fp32 final out
        } else {
          const short v = f2b(acc[i][j][rr]);
          const int b = m >> 11, s = m & 2047;
          const int h = n >> 7, d = n & 127;
          if (blockIdx.z == 0)
            ((short*)O0)[((size_t)(b * 16 + h) * 2048 + s) * 128 + d] = v;  // Q
          else if (blockIdx.z == 1)
            O1[((size_t)(b * 16 + h) * 2048 + s) * 128 + d] = v;  // K [B,H,S,D]
          else
            O2[((size_t)(b * 16 + h) * 128 + d) * 2048 + s] = v;  // V^T [B,H,D,S]
        }
      }
    }
  }
}

// RoPE in place on Q and K ([B,H,S,D] bf16); thread handles pair (d, d+64).
// R5: Q additionally pre-scaled by rscale*log2(e) = 0.12751743 so attn's
// QK^T lands directly in exp2-domain softmax units (no per-element muls).
__global__ void rope_kernel(short* __restrict__ Q,
                            short* __restrict__ Kb,
                            const int* __restrict__ pos_ids) {
  const int idx = blockIdx.x * 256 + threadIdx.x;  // 2*2*16*2048*64 total
  const int d = idx & 63;
  const int row = idx >> 6;       // 0..131071 over {Q,K} x [B,H,S]
  const int tsel = row >> 16;
  const int r = row & 65535;      // (b*16+h)*2048 + s
  const int s = r & 2047;
  const int b = r >> 15;
  const int pos = pos_ids[b * 2048 + s];
  // 10000^(-d/64) = 2^(-d * log2(10000)/64)
  const float invf = __builtin_exp2f(-(float)d * 0.20762050593117475f);
  const float ang = (float)pos * invf;
  const float c = cosf(ang), sn = sinf(ang);
  const float qs = tsel ? 1.0f : 0.12751743f;  // log2(e)/sqrt(128) on Q only
  short* P = (tsel ? Kb : Q) + (size_t)r * 128;
  const float x1 = b2f(P[d]);
  const float x2 = b2f(P[d + 64]);
  P[d] = f2b((x1 * c - x2 * sn) * qs);
  P[d + 64] = f2b((x2 * c + x1 * sn) * qs);
}

// Flash attention, causal. Block = 4 waves = 64 q rows; kv tiles of 32,
// double-buffered via global_load_lds, one __syncthreads per tile.
// R5 core: SWAPPED QK^T — sc = mfma(kf, qf) so D(col=lane&15=q-ln,
// row=qd*4+rr=k). Each lane owns one q-row (q=qw0+ln): row-max/row-sum are
// 7 lane-local ops + 2 shfl_xor(16,32); m,l are per-lane scalars; softmax in
// exp2-domain (scale folded into Q at rope). P->A-frag repack fully
// in-register: 4 v_cvt_pk_bf16_f32 + 8 shfl + 4 selects (dest quad qdd pulls
// k=8*qdd..+7 from src quads 2(qdd&1),+1 at lanes ln+32(qdd&1),+16; A(j=0)
// for qdd<2 else B(j=1)). No P LDS buffer (LDS 32768 B), no ones-MFMA,
// no psum shuffles. oacc alphas / final 1/l redistributed via 4 shfl.
// Grid map (R4): XCD-local heads + per-CU balanced qt. Defer-max THR=8 (log2).
__global__ __launch_bounds__(256, 5) void attn_kernel(
    const short* __restrict__ Q,
    const short* __restrict__ Kbuf,
    const short* __restrict__ Vt,
    short* __restrict__ O) {
  const int n = blockIdx.x;           // 0..1023
  const int xcd = n & 7;
  const int m_ = n >> 3;
  const int bh = xcd + 8 * (m_ & 3);
  const int x_ = m_ >> 2;             // 0..31
  const int u_ = x_ & 7;
  const int g_ = x_ >> 3;             // 0..3
  const int qt = (g_ == 0) ? 2 * u_
               : (g_ == 1) ? 31 - 2 * u_
               : (g_ == 2) ? 2 * u_ + 1
                           : 30 - 2 * u_;
  const int q0 = qt * 64;
  const size_t hoff = (size_t)bh * 2048 * 128;
  const short* Qh = Q + hoff;
  const short* Kh = Kbuf + hoff;
  const short* Vh = Vt + hoff;

  __shared__ __align__(16) short Ks[2][32 * 128];  // [buf][kv][16 gran, swz]
  __shared__ __align__(16) short Vs[2][128 * 32];  // [buf][d][4 gran, depth-2 swz]

  const int t = threadIdx.x;
  const int wave = t >> 6;
  const int lane = t & 63;
  const int qd = lane >> 4;
  const int ln = lane & 15;
  const int qw0 = q0 + wave * 16;

  bf16x8 qf[4];
  {
    const short* qp = Qh + (size_t)(qw0 + ln) * 128 + qd * 8;
#pragma unroll
    for (int kc = 0; kc < 4; ++kc) qf[kc] = *(const bf16x8*)(qp + kc * 32);
  }

  const f32x4 zero = {0.f, 0.f, 0.f, 0.f};
  f32x4 oacc[8];
#pragma unroll
  for (int dt = 0; dt < 8; ++dt) oacc[dt] = zero;
  float mrow = -1e30f;  // per-lane: q-row qw0+ln, log2 units
  float lrow = 0.f;

  // staging geometry (global src pre-swizzled; LDS dest linear per async16):
  // K round rd: row rd*16 + (t>>4), slot t&15, gran = slot^(row&7)
  // V round rd: d-row rd*64 + (t>>2), slot t&3, gran = slot^(row&3)^((row>>2)&3)
  const int kr = t >> 4;
  const int gk = (t & 15) ^ (kr & 7);
  const int vr = t >> 2;
  const int gv = (t & 3) ^ (vr & 3) ^ ((vr >> 2) & 3);
  const short* Kg = Kh + (size_t)kr * 128 + gk * 8;
  const short* Vg = Vh + (size_t)vr * 2048 + gv * 8;
  const int wb = wave * 512;  // per-wave LDS staging base (lane*16B implicit)

  const int nkv = 2 * qt + 2;

  // prologue: stage tile 0 -> buf 0
#pragma unroll
  for (int rd = 0; rd < 2; ++rd) {
    async16(Kg + (size_t)(rd * 16) * 128, &Ks[0][rd * 2048 + wb]);
    async16(Vg + (size_t)rd * 131072, &Vs[0][rd * 2048 + wb]);
  }

  int cur = 0;
  for (int kt = 0; kt < nkv; ++kt) {
    const int k0 = kt * 32;
    __syncthreads();  // vmcnt(0) drain: buf[cur] ready; prior buf[cur^1] reads done
    if (kt + 1 < nkv) {
      const int k1 = k0 + 32;
#pragma unroll
      for (int rd = 0; rd < 2; ++rd) {
        async16(Kg + (size_t)(k1 + rd * 16) * 128, &Ks[cur ^ 1][rd * 2048 + wb]);
        async16(Vg + (size_t)rd * 131072 + k1, &Vs[cur ^ 1][rd * 2048 + wb]);
      }
    }

    if (k0 <= qw0 + 15) {  // wave-uniform: skip fully-masked diagonal subtile
      const short* Kc = &Ks[cur][0];
      // S^T = K Q^T: sc[j][rr] = S(q = qw0+ln, k = k0 + 16j + 4qd + rr)
      f32x4 sc[2];
#pragma unroll
      for (int j = 0; j < 2; ++j) {
        sc[j] = zero;
        const int krow = j * 16 + ln;
#pragma unroll
        for (int kc = 0; kc < 4; ++kc) {
          const bf16x8 kf =
              *(const bf16x8*)&Kc[krow * 128 + (((kc * 4 + qd) ^ (krow & 7)) << 3)];
          sc[j] = __builtin_amdgcn_mfma_f32_16x16x32_bf16(kf, qf[kc], sc[j], 0, 0, 0);
        }
      }

      float pvv[2][4];
#pragma unroll
      for (int j = 0; j < 2; ++j)
#pragma unroll
        for (int rr = 0; rr < 4; ++rr) pvv[j][rr] = sc[j][rr];
      if (k0 + 31 > qw0) {  // wave-uniform: partial mask (any col > min row)
        const int qrow = qw0 + ln;
#pragma unroll
        for (int j = 0; j < 2; ++j)
#pragma unroll
          for (int rr = 0; rr < 4; ++rr)
            if (k0 + j * 16 + qd * 4 + rr > qrow) pvv[j][rr] = -1e30f;
      }

      // row-max: lane-local 8 then across the 4 quads of this q-row
      float tmax = pvv[0][0];
#pragma unroll
      for (int j = 0; j < 2; ++j)
#pragma unroll
        for (int rr = 0; rr < 4; ++rr) tmax = fmaxf(tmax, pvv[j][rr]);
      tmax = fmaxf(tmax, __shfl_xor(tmax, 16));
      tmax = fmaxf(tmax, __shfl_xor(tmax, 32));

      // defer-max: rescale only when max grew by > 8 (log2 units)
      if (__any(tmax > mrow + 8.f)) {
        const float mnew = fmaxf(mrow, tmax);
        const float al = __builtin_exp2f(mrow - mnew);
        mrow = mnew;
        lrow *= al;
        float a[4];
#pragma unroll
        for (int rr = 0; rr < 4; ++rr) a[rr] = __shfl(al, qd * 4 + rr);
#pragma unroll
        for (int dt = 0; dt < 8; ++dt)
#pragma unroll
          for (int rr = 0; rr < 4; ++rr) oacc[dt][rr] *= a[rr];
      }

      // P = 2^(s - m); row-sum lane-local + cross-quad
      float ps = 0.f;
#pragma unroll
      for (int j = 0; j < 2; ++j)
#pragma unroll
        for (int rr = 0; rr < 4; ++rr) {
          const float p = __builtin_exp2f(pvv[j][rr] - mrow);
          pvv[j][rr] = p;
          ps += p;
        }
      ps += __shfl_xor(ps, 16);
      ps += __shfl_xor(ps, 32);
      lrow += ps;

      // pack to bf16 pairs (k-order) and repack to x32 A-frag in-register
      const unsigned A0 = cvtpk(pvv[0][0], pvv[0][1]);
      const unsigned A1 = cvtpk(pvv[0][2], pvv[0][3]);
      const unsigned B0 = cvtpk(pvv[1][0], pvv[1][1]);
      const unsigned B1 = cvtpk(pvv[1][2], pvv[1][3]);
      const int s0 = ln + ((qd & 1) << 5);  // src lane low
      const int s1 = s0 + 16;               // src lane high
      const unsigned a0 = __shfl(A0, s0), a1 = __shfl(A1, s0);
      const unsigned a2 = __shfl(A0, s1), a3 = __shfl(A1, s1);
      const unsigned b0 = __shfl(B0, s0), b1 = __shfl(B1, s0);
      const unsigned b2 = __shfl(B0, s1), b3 = __shfl(B1, s1);
      const bool useA = (qd < 2);
      u32x4 pr;
      pr[0] = useA ? a0 : b0;
      pr[1] = useA ? a1 : b1;
      pr[2] = useA ? a2 : b2;
      pr[3] = useA ? a3 : b3;
      const bf16x8 pf = __builtin_bit_cast(bf16x8, pr);

      // O += P V  (8 d-tiles)
      const short* Vc = &Vs[cur][0];
#pragma unroll
      for (int dt = 0; dt < 8; ++dt) {
        const int d = dt * 16 + ln;
        const bf16x8 vf =
            *(const bf16x8*)&Vc[d * 32 + (((qd ^ (d & 3) ^ ((d >> 2) & 3)) << 3))];
        oacc[dt] = __builtin_amdgcn_mfma_f32_16x16x32_bf16(pf, vf, oacc[dt], 0, 0, 0);
      }
    }
    cur ^= 1;
  }

  const int b = bh >> 4;
  const int h = bh & 15;
  float rl[4];
#pragma unroll
  for (int rr = 0; rr < 4; ++rr) rl[rr] = 1.0f / __shfl(lrow, qd * 4 + rr);
#pragma unroll
  for (int dt = 0; dt < 8; ++dt) {
    const int d = dt * 16 + ln;
#pragma unroll
    for (int rr = 0; rr < 4; ++rr) {
      const int q = qw0 + qd * 4 + rr;
      O[((size_t)(b * 2048 + q)) * 2048 + h * 128 + d] = f2b(oacc[dt][rr] * rl[rr]);
    }
  }
}

extern "C" void kernel_launch(void* const* d_in, const int* in_sizes, int n_in,
                              void* d_out, int out_size, void* d_ws, size_t ws_size,
                              hipStream_t stream) {
  const float* X  = (const float*)d_in[0];  // hidden_states [2,2048,2048] fp32
  // d_in[1] attention_mask: causal, implemented analytically (unused)
  const int* pos  = (const int*)d_in[2];    // position_ids [2,2048] int32
  const float* Wq = (const float*)d_in[3];  // [2048,2048] fp32
  const float* Wk = (const float*)d_in[4];
  const float* Wv = (const float*)d_in[5];
  const float* Wo = (const float*)d_in[6];
  float* out = (float*)d_out;               // fp32 output

  short* ws = (short*)d_ws;
  // bf16 workspace layout (shorts):
  short* Xb  = ws;                       // 8388608
  short* Wqb = ws + 8388608;             // 4194304
  short* Wkb = Wqb + 4194304;
  short* Wvb = Wkb + 4194304;
  short* Wob = Wvb + 4194304;
  short* Qb  = Wob + 4194304;            // 8388608
  short* Kb  = Qb + 8388608;
  short* Vt  = Kb + 8388608;
  short* Ob  = Vt + 8388608;             // total ~112 MB

  cvt_kernel<<<dim3(12288), 256, 0, stream>>>(X, Wq, Wk, Wv, Wo, Xb);
  gemm_kernel<0><<<dim3(32, 16, 3), 256, 0, stream>>>(Xb, Wqb, Wkb, Wvb,
                                                      Qb, Kb, Vt);
  rope_kernel<<<dim3(32768), 256, 0, stream>>>(Qb, Kb, pos);
  attn_kernel<<<dim3(1024), 256, 0, stream>>>(Qb, Kb, Vt, Ob);
  gemm_kernel<1><<<dim3(32, 16, 1), 256, 0, stream>>>(Ob, Wob, nullptr, nullptr,
                                                      out, nullptr, nullptr);
}

// Round 6
// 396.738 us; speedup vs baseline: 1.0805x; 1.0805x over previous
//
#include <hip/hip_runtime.h>
#include <hip/hip_bf16.h>

typedef __attribute__((ext_vector_type(4))) float f32x4;
typedef __attribute__((ext_vector_type(8))) short bf16x8;
typedef __attribute__((ext_vector_type(4))) unsigned u32x4;

__device__ __forceinline__ short f2b(float f) {  // fp32 -> bf16 bits, RNE
  unsigned u = __builtin_bit_cast(unsigned, f);
  u += 0x7FFFu + ((u >> 16) & 1u);
  return (short)(u >> 16);
}
__device__ __forceinline__ float b2f(short s) {
  unsigned u = ((unsigned)(unsigned short)s) << 16;
  return __builtin_bit_cast(float, u);
}
__device__ __forceinline__ unsigned cvtpk(float lo, float hi) {  // 2xf32->2xbf16
  unsigned r;
  asm("v_cvt_pk_bf16_f32 %0, %1, %2" : "=v"(r) : "v"(lo), "v"(hi));
  return r;
}

__device__ __forceinline__ void async16(const void* g, void* l) {
  __builtin_amdgcn_global_load_lds(
      (const __attribute__((address_space(1))) void*)g,
      (__attribute__((address_space(3))) void*)l, 16, 0, 0);
}

#define BM 128
#define BN 128
#define BK 64

// Convert fp32 inputs to bf16 workspace: X (8388608 el) then Wq/Wk/Wv/Wo
// (4194304 el each). R6: tail blocks (u >= 3145728) fill RoPE cos/sin
// tables [2048 pos][64 d] f32 so the fused gemm epilogue needs no trig.
__global__ __launch_bounds__(256) void cvt_kernel(
    const float* __restrict__ X, const float* __restrict__ Wq,
    const float* __restrict__ Wk, const float* __restrict__ Wv,
    const float* __restrict__ Wo, short* __restrict__ dst,
    float* __restrict__ Tc, float* __restrict__ Ts) {
  const size_t u = (size_t)blockIdx.x * 256 + threadIdx.x;  // unit of 8 elems
  if (u >= 3145728) {               // table tail: 131072 threads
    const int idx = (int)(u - 3145728);
    const int pos = idx >> 6, d = idx & 63;
    // 10000^(-d/64) = 2^(-d * log2(10000)/64)
    const float invf = __builtin_exp2f(-(float)d * 0.20762050593117475f);
    const float ang = (float)pos * invf;
    Tc[idx] = cosf(ang);
    Ts[idx] = sinf(ang);
    return;
  }
  const float* src;
  short* d;
  size_t off;
  if (u < 1048576) {                // X: 1048576 units
    src = X; d = dst; off = u * 8;
  } else {
    const size_t j = u - 1048576;   // 4 x 524288 units
    const int ten = (int)(j >> 19);
    off = (j & 524287) * 8;
    src = (ten == 0) ? Wq : (ten == 1) ? Wk : (ten == 2) ? Wv : Wo;
    d = dst + 8388608 + (size_t)ten * 4194304;
  }
  const f32x4 lo = *(const f32x4*)(src + off);
  const f32x4 hi = *(const f32x4*)(src + off + 4);
  bf16x8 v;
#pragma unroll
  for (int i = 0; i < 4; ++i) { v[i] = f2b(lo[i]); v[i + 4] = f2b(hi[i]); }
  *(bf16x8*)(d + off) = v;
}

// C = A[M,K] @ B[N,K]^T, all-bf16 operands, global_load_lds staging (m97).
// MODE 0: z selects Wq/Wk/Wv; epilogue scatters Q,K [B,H,S,D], V^T [B,H,D,S].
//   R6: RoPE FUSED into the Q/K (z=0/1) epilogue. Thread owning (s,d) needs
//   x at d^64 -> pure wave-pair swap (wc^1, same lane & acc idx) through the
//   retired As/Bs LDS (2 rounds x 16KB, element-major -> conflict-free).
//   cos/sin from precomputed tables; Q pre-scaled by log2(e)/sqrt(128).
// MODE 1: fp32 row-major output [M,2048] -> d_out.
template <int MODE>
__global__ __launch_bounds__(256, 2) void gemm_kernel(
    const short* __restrict__ A,
    const short* __restrict__ B0,
    const short* __restrict__ B1,
    const short* __restrict__ B2,
    void* __restrict__ O0,
    short* __restrict__ O1,
    short* __restrict__ O2,
    const int* __restrict__ pos_ids,
    const float* __restrict__ Tc,
    const float* __restrict__ Ts) {
  constexpr int K = 2048;
  const int m0 = blockIdx.x * BM;
  const int n0 = blockIdx.y * BN;
  const short* B;
  if (MODE == 0) {
    const int wsel = blockIdx.z;
    B = (wsel == 0) ? B0 : ((wsel == 1) ? B1 : B2);
  } else {
    B = B0;
  }

  __shared__ __align__(16) short As[BM * BK];  // [row][8 granules, XOR-swizzled]
  __shared__ __align__(16) short Bs[BN * BK];

  const int t = threadIdx.x;
  const int wave = t >> 6;
  const int lane = t & 63;
  const int qd = lane >> 4;  // quad 0..3
  const int ln = lane & 15;
  const int wr = wave >> 1;
  const int wc = wave & 1;

  const f32x4 zero = {0.f, 0.f, 0.f, 0.f};
  f32x4 acc[4][4];
#pragma unroll
  for (int i = 0; i < 4; ++i)
#pragma unroll
    for (int j = 0; j < 4; ++j) acc[i][j] = zero;

  // staging: round r covers row r*32 + (t>>3); LDS slot t&7 holds global
  // granule (t&7)^(row&7). LDS elem for (t, r): r*2048 + t*8 = row*64 + slot*8.
  // LDS dest = wave-uniform base + lane*16B (async16 constraint) ✓
  const int srow = t >> 3;
  const int sgp = (t & 7) ^ (srow & 7);
  const short* Ag = A + (size_t)(m0 + srow) * K + sgp * 8;
  const short* Bg = B + (size_t)(n0 + srow) * K + sgp * 8;
  short* Asw = &As[wave * 512];
  short* Bsw = &Bs[wave * 512];

  for (int k0 = 0; k0 < K; k0 += BK) {
    __syncthreads();
#pragma unroll
    for (int r = 0; r < 4; ++r) {
      async16(Ag + (size_t)(r * 32) * K + k0, Asw + r * 2048);
      async16(Bg + (size_t)(r * 32) * K + k0, Bsw + r * 2048);
    }
    __syncthreads();

    bf16x8 af[2][4], bf[2][4];
#pragma unroll
    for (int kc = 0; kc < 2; ++kc) {
#pragma unroll
      for (int i = 0; i < 4; ++i) {
        const int m = wr * 64 + i * 16 + ln;
        af[kc][i] = *(const bf16x8*)&As[m * BK + (((kc * 4 + qd) ^ (m & 7)) << 3)];
        const int n = wc * 64 + i * 16 + ln;
        bf[kc][i] = *(const bf16x8*)&Bs[n * BK + (((kc * 4 + qd) ^ (n & 7)) << 3)];
      }
    }
#pragma unroll
    for (int kc = 0; kc < 2; ++kc)
#pragma unroll
      for (int i = 0; i < 4; ++i)
#pragma unroll
        for (int j = 0; j < 4; ++j)
          acc[i][j] = __builtin_amdgcn_mfma_f32_16x16x32_bf16(af[kc][i], bf[kc][j],
                                                              acc[i][j], 0, 0, 0);
  }

  // epilogue; C/D layout: col = lane&15, row = quad*4 + reg (m89/m91 verified)
  if (MODE == 0 && blockIdx.z != 2) {
    // ---- RoPE-fused Q/K epilogue (block-uniform branch) ----
    float* fx = (float*)As;  // 32KB retired staging LDS
    const float qs = (blockIdx.z == 0) ? 0.12751743f : 1.0f;  // log2e/sqrt(128)
    short* Od = (blockIdx.z == 0) ? (short*)O0 : O1;
    const int h = n0 >> 7;   // head fixed per block (BN=128)
    const int pt = t ^ 64;   // partner thread: wave^1, same lane
#pragma unroll
    for (int round = 0; round < 2; ++round) {
      __syncthreads();  // waves done with As/Bs (or prior round's reads)
#pragma unroll
      for (int ii = 0; ii < 2; ++ii)
#pragma unroll
        for (int j = 0; j < 4; ++j)
#pragma unroll
          for (int rr = 0; rr < 4; ++rr)
            fx[(ii * 16 + j * 4 + rr) * 256 + t] = acc[round * 2 + ii][j][rr];
      __syncthreads();
#pragma unroll
      for (int ii = 0; ii < 2; ++ii) {
        const int i = round * 2 + ii;
#pragma unroll
        for (int rr = 0; rr < 4; ++rr) {
          const int m = m0 + wr * 64 + i * 16 + qd * 4 + rr;
          const int b = m >> 11, s = m & 2047;
          const int pos = pos_ids[b * 2048 + s];
#pragma unroll
          for (int j = 0; j < 4; ++j) {
            const int dd = j * 16 + ln;        // d mod 64
            const float c = Tc[pos * 64 + dd];
            const float sn = Ts[pos * 64 + dd];
            const float x = acc[i][j][rr];
            const float xp = fx[(ii * 16 + j * 4 + rr) * 256 + pt];
            // d<64 (wc=0): x*c - x[d+64]*s ; d>=64 (wc=1): x*c + x[d-64]*s
            const float val = wc ? (x * c + xp * sn) : (x * c - xp * sn);
            const int d = wc * 64 + dd;
            Od[((size_t)(b * 16 + h) * 2048 + s) * 128 + d] = f2b(val * qs);
          }
        }
      }
    }
  } else {
#pragma unroll
    for (int i = 0; i < 4; ++i) {
#pragma unroll
      for (int j = 0; j < 4; ++j) {
        const int n = n0 + wc * 64 + j * 16 + ln;
#pragma unroll
        for (int rr = 0; rr < 4; ++rr) {
          const int m = m0 + wr * 64 + i * 16 + qd * 4 + rr;
          if (MODE == 1) {
            ((float*)O0)[(size_t)m * 2048 + n] = acc[i][j][rr];  // fp32 final out
          } else {
            const short v = f2b(acc[i][j][rr]);
            const int b = m >> 11, s = m & 2047;
            const int h = n >> 7, d = n & 127;
            O2[((size_t)(b * 16 + h) * 128 + d) * 2048 + s] = v;  // V^T [B,H,D,S]
          }
        }
      }
    }
  }
}

// Flash attention, causal. Block = 4 waves = 64 q rows; kv tiles of 32,
// double-buffered via global_load_lds, one __syncthreads per tile.
// Swapped QK^T core (R5): sc = mfma(kf, qf) -> lane owns one q-row; softmax
// in exp2-domain (scale folded into Q at the fused rope); in-register P
// repack via v_cvt_pk_bf16_f32 + shfl. Grid map (R4): XCD-local heads +
// per-CU balanced qt. Defer-max THR=8 (log2 units).
__global__ __launch_bounds__(256, 5) void attn_kernel(
    const short* __restrict__ Q,
    const short* __restrict__ Kbuf,
    const short* __restrict__ Vt,
    short* __restrict__ O) {
  const int n = blockIdx.x;           // 0..1023
  const int xcd = n & 7;
  const int m_ = n >> 3;
  const int bh = xcd + 8 * (m_ & 3);
  const int x_ = m_ >> 2;             // 0..31
  const int u_ = x_ & 7;
  const int g_ = x_ >> 3;             // 0..3
  const int qt = (g_ == 0) ? 2 * u_
               : (g_ == 1) ? 31 - 2 * u_
               : (g_ == 2) ? 2 * u_ + 1
                           : 30 - 2 * u_;
  const int q0 = qt * 64;
  const size_t hoff = (size_t)bh * 2048 * 128;
  const short* Qh = Q + hoff;
  const short* Kh = Kbuf + hoff;
  const short* Vh = Vt + hoff;

  __shared__ __align__(16) short Ks[2][32 * 128];  // [buf][kv][16 gran, swz]
  __shared__ __align__(16) short Vs[2][128 * 32];  // [buf][d][4 gran, depth-2 swz]

  const int t = threadIdx.x;
  const int wave = t >> 6;
  const int lane = t & 63;
  const int qd = lane >> 4;
  const int ln = lane & 15;
  const int qw0 = q0 + wave * 16;

  bf16x8 qf[4];
  {
    const short* qp = Qh + (size_t)(qw0 + ln) * 128 + qd * 8;
#pragma unroll
    for (int kc = 0; kc < 4; ++kc) qf[kc] = *(const bf16x8*)(qp + kc * 32);
  }

  const f32x4 zero = {0.f, 0.f, 0.f, 0.f};
  f32x4 oacc[8];
#pragma unroll
  for (int dt = 0; dt < 8; ++dt) oacc[dt] = zero;
  float mrow = -1e30f;  // per-lane: q-row qw0+ln, log2 units
  float lrow = 0.f;

  // staging geometry (global src pre-swizzled; LDS dest linear per async16):
  // K round rd: row rd*16 + (t>>4), slot t&15, gran = slot^(row&7)
  // V round rd: d-row rd*64 + (t>>2), slot t&3, gran = slot^(row&3)^((row>>2)&3)
  const int kr = t >> 4;
  const int gk = (t & 15) ^ (kr & 7);
  const int vr = t >> 2;
  const int gv = (t & 3) ^ (vr & 3) ^ ((vr >> 2) & 3);
  const short* Kg = Kh + (size_t)kr * 128 + gk * 8;
  const short* Vg = Vh + (size_t)vr * 2048 + gv * 8;
  const int wb = wave * 512;  // per-wave LDS staging base (lane*16B implicit)

  const int nkv = 2 * qt + 2;

  // prologue: stage tile 0 -> buf 0
#pragma unroll
  for (int rd = 0; rd < 2; ++rd) {
    async16(Kg + (size_t)(rd * 16) * 128, &Ks[0][rd * 2048 + wb]);
    async16(Vg + (size_t)rd * 131072, &Vs[0][rd * 2048 + wb]);
  }

  int cur = 0;
  for (int kt = 0; kt < nkv; ++kt) {
    const int k0 = kt * 32;
    __syncthreads();  // vmcnt(0) drain: buf[cur] ready; prior buf[cur^1] reads done
    if (kt + 1 < nkv) {
      const int k1 = k0 + 32;
#pragma unroll
      for (int rd = 0; rd < 2; ++rd) {
        async16(Kg + (size_t)(k1 + rd * 16) * 128, &Ks[cur ^ 1][rd * 2048 + wb]);
        async16(Vg + (size_t)rd * 131072 + k1, &Vs[cur ^ 1][rd * 2048 + wb]);
      }
    }

    if (k0 <= qw0 + 15) {  // wave-uniform: skip fully-masked diagonal subtile
      const short* Kc = &Ks[cur][0];
      // S^T = K Q^T: sc[j][rr] = S(q = qw0+ln, k = k0 + 16j + 4qd + rr)
      f32x4 sc[2];
#pragma unroll
      for (int j = 0; j < 2; ++j) {
        sc[j] = zero;
        const int krow = j * 16 + ln;
#pragma unroll
        for (int kc = 0; kc < 4; ++kc) {
          const bf16x8 kf =
              *(const bf16x8*)&Kc[krow * 128 + (((kc * 4 + qd) ^ (krow & 7)) << 3)];
          sc[j] = __builtin_amdgcn_mfma_f32_16x16x32_bf16(kf, qf[kc], sc[j], 0, 0, 0);
        }
      }

      float pvv[2][4];
#pragma unroll
      for (int j = 0; j < 2; ++j)
#pragma unroll
        for (int rr = 0; rr < 4; ++rr) pvv[j][rr] = sc[j][rr];
      if (k0 + 31 > qw0) {  // wave-uniform: partial mask (any col > min row)
        const int qrow = qw0 + ln;
#pragma unroll
        for (int j = 0; j < 2; ++j)
#pragma unroll
          for (int rr = 0; rr < 4; ++rr)
            if (k0 + j * 16 + qd * 4 + rr > qrow) pvv[j][rr] = -1e30f;
      }

      // row-max: lane-local 8 then across the 4 quads of this q-row
      float tmax = pvv[0][0];
#pragma unroll
      for (int j = 0; j < 2; ++j)
#pragma unroll
        for (int rr = 0; rr < 4; ++rr) tmax = fmaxf(tmax, pvv[j][rr]);
      tmax = fmaxf(tmax, __shfl_xor(tmax, 16));
      tmax = fmaxf(tmax, __shfl_xor(tmax, 32));

      // defer-max: rescale only when max grew by > 8 (log2 units)
      if (__any(tmax > mrow + 8.f)) {
        const float mnew = fmaxf(mrow, tmax);
        const float al = __builtin_exp2f(mrow - mnew);
        mrow = mnew;
        lrow *= al;
        float a[4];
#pragma unroll
        for (int rr = 0; rr < 4; ++rr) a[rr] = __shfl(al, qd * 4 + rr);
#pragma unroll
        for (int dt = 0; dt < 8; ++dt)
#pragma unroll
          for (int rr = 0; rr < 4; ++rr) oacc[dt][rr] *= a[rr];
      }

      // P = 2^(s - m); row-sum lane-local + cross-quad
      float ps = 0.f;
#pragma unroll
      for (int j = 0; j < 2; ++j)
#pragma unroll
        for (int rr = 0; rr < 4; ++rr) {
          const float p = __builtin_exp2f(pvv[j][rr] - mrow);
          pvv[j][rr] = p;
          ps += p;
        }
      ps += __shfl_xor(ps, 16);
      ps += __shfl_xor(ps, 32);
      lrow += ps;

      // pack to bf16 pairs (k-order) and repack to x32 A-frag in-register
      const unsigned A0 = cvtpk(pvv[0][0], pvv[0][1]);
      const unsigned A1 = cvtpk(pvv[0][2], pvv[0][3]);
      const unsigned B0 = cvtpk(pvv[1][0], pvv[1][1]);
      const unsigned B1 = cvtpk(pvv[1][2], pvv[1][3]);
      const int s0 = ln + ((qd & 1) << 5);  // src lane low
      const int s1 = s0 + 16;               // src lane high
      const unsigned a0 = __shfl(A0, s0), a1 = __shfl(A1, s0);
      const unsigned a2 = __shfl(A0, s1), a3 = __shfl(A1, s1);
      const unsigned b0 = __shfl(B0, s0), b1 = __shfl(B1, s0);
      const unsigned b2 = __shfl(B0, s1), b3 = __shfl(B1, s1);
      const bool useA = (qd < 2);
      u32x4 pr;
      pr[0] = useA ? a0 : b0;
      pr[1] = useA ? a1 : b1;
      pr[2] = useA ? a2 : b2;
      pr[3] = useA ? a3 : b3;
      const bf16x8 pf = __builtin_bit_cast(bf16x8, pr);

      // O += P V  (8 d-tiles)
      const short* Vc = &Vs[cur][0];
#pragma unroll
      for (int dt = 0; dt < 8; ++dt) {
        const int d = dt * 16 + ln;
        const bf16x8 vf =
            *(const bf16x8*)&Vc[d * 32 + (((qd ^ (d & 3) ^ ((d >> 2) & 3)) << 3))];
        oacc[dt] = __builtin_amdgcn_mfma_f32_16x16x32_bf16(pf, vf, oacc[dt], 0, 0, 0);
      }
    }
    cur ^= 1;
  }

  const int b = bh >> 4;
  const int h = bh & 15;
  float rl[4];
#pragma unroll
  for (int rr = 0; rr < 4; ++rr) rl[rr] = 1.0f / __shfl(lrow, qd * 4 + rr);
#pragma unroll
  for (int dt = 0; dt < 8; ++dt) {
    const int d = dt * 16 + ln;
#pragma unroll
    for (int rr = 0; rr < 4; ++rr) {
      const int q = qw0 + qd * 4 + rr;
      O[((size_t)(b * 2048 + q)) * 2048 + h * 128 + d] = f2b(oacc[dt][rr] * rl[rr]);
    }
  }
}

extern "C" void kernel_launch(void* const* d_in, const int* in_sizes, int n_in,
                              void* d_out, int out_size, void* d_ws, size_t ws_size,
                              hipStream_t stream) {
  const float* X  = (const float*)d_in[0];  // hidden_states [2,2048,2048] fp32
  // d_in[1] attention_mask: causal, implemented analytically (unused)
  const int* pos  = (const int*)d_in[2];    // position_ids [2,2048] int32
  const float* Wq = (const float*)d_in[3];  // [2048,2048] fp32
  const float* Wk = (const float*)d_in[4];
  const float* Wv = (const float*)d_in[5];
  const float* Wo = (const float*)d_in[6];
  float* out = (float*)d_out;               // fp32 output

  short* ws = (short*)d_ws;
  // bf16 workspace layout (shorts):
  short* Xb  = ws;                       // 8388608
  short* Wqb = ws + 8388608;             // 4194304
  short* Wkb = Wqb + 4194304;
  short* Wvb = Wkb + 4194304;
  short* Wob = Wvb + 4194304;
  short* Qb  = Wob + 4194304;            // 8388608
  short* Kb  = Qb + 8388608;
  short* Vt  = Kb + 8388608;
  short* Ob  = Vt + 8388608;             // 8388608
  float* Tc  = (float*)(Ob + 8388608);   // 131072 f32 (rope cos table)
  float* Ts  = Tc + 131072;              // 131072 f32 (rope sin table)
  // total ~118.5 MB

  // 12800 blocks: 12288 convert + 512 table-fill
  cvt_kernel<<<dim3(12800), 256, 0, stream>>>(X, Wq, Wk, Wv, Wo, Xb, Tc, Ts);
  gemm_kernel<0><<<dim3(32, 16, 3), 256, 0, stream>>>(Xb, Wqb, Wkb, Wvb,
                                                      Qb, Kb, Vt, pos, Tc, Ts);
  attn_kernel<<<dim3(1024), 256, 0, stream>>>(Qb, Kb, Vt, Ob);
  gemm_kernel<1><<<dim3(32, 16, 1), 256, 0, stream>>>(Ob, Wob, nullptr, nullptr,
                                                      out, nullptr, nullptr,
                                                      nullptr, nullptr, nullptr);
}